// Round 11
// baseline (210.326 us; speedup 1.0000x reference)
//
#include <hip/hip_runtime.h>

#define N_NODES 100000
#define N_EDGES 1600000
#define IN_DIM  192
#define H1      64
#define H2      32
#define NBKT    391          // ceil(N_NODES/256) buckets (both dst- and src-keyed)
#define CAP_D   4608         // bucket capacity (mean 4096, sigma 64 -> 8 sigma)
#define NP1     196          // ceil(N_EDGES/8192) pass1 blocks
#define K1GRID  1759         // b%9==0 -> pass1 (196), else gemm1 (1563)

typedef __attribute__((ext_vector_type(8))) short short8;
typedef __attribute__((ext_vector_type(4))) float f32x4;

__device__ inline short f2bf(float f) {
    union { float f; unsigned u; } v; v.f = f;
    unsigned r = (v.u + 0x7FFFu + ((v.u >> 16) & 1u)) >> 16;
    return (short)r;
}
__device__ inline float bf2f(unsigned short s) {
    union { unsigned u; float f; } v; v.u = ((unsigned)s) << 16;
    return v.f;
}

// ------- weight prep: Bt1[128][192], Bt2[64][64], bf16, N-major; block 0 inits cursors -------
__global__ __launch_bounds__(256) void prep_w_kernel(
    const float* __restrict__ W0_1, const float* __restrict__ W1_1,
    const float* __restrict__ W0_2, const float* __restrict__ W1_2,
    short* __restrict__ Bt1, short* __restrict__ Bt2, int* __restrict__ bucket_next) {
    if (blockIdx.x == 0) {
        for (int i = threadIdx.x; i < 1024; i += 256)
            bucket_next[i] = (i & 511) * CAP_D;
    }
    int idx = blockIdx.x * 256 + threadIdx.x;
    if (idx < 128 * IN_DIM) {
        int n = idx / IN_DIM, k = idx % IN_DIM;
        float v = (n < H1) ? W0_1[(size_t)k * H1 + n] : W1_1[(size_t)k * H1 + (n - H1)];
        Bt1[idx] = f2bf(v);
    } else {
        int j = idx - 128 * IN_DIM;
        if (j < 64 * H1) {
            int n = j / H1, k = j % H1;
            float v = (n < H2) ? W0_2[(size_t)k * H2 + n] : W1_2[(size_t)k * H2 + (n - H2)];
            Bt2[j] = f2bf(v);
        }
    }
}

// ---- K1 fused: pass1 dual binning (8192 edges/block, 3-phase) || gemm1 MFMA ----
__global__ __launch_bounds__(256) void k1_fused(
    const int* __restrict__ edges, int* __restrict__ bucket_next,
    int* __restrict__ bins_dst, unsigned char* __restrict__ bins_src,
    const float* __restrict__ verts, const short* __restrict__ Bt1,
    const float* __restrict__ b1, short* __restrict__ hbase, short* __restrict__ y1b) {
    __shared__ int cntd[512];
    __shared__ int curd[512];
    __shared__ int cnts[512];
    __shared__ int curs[512];
    int b = blockIdx.x;
    int tid = threadIdx.x;
    if (b % 9 == 0) {
        // ---------------- pass1 role: 8192 edges ----------------
        int p = b / 9;                       // 0..195
        cntd[tid] = 0; cntd[tid + 256] = 0;
        cnts[tid] = 0; cnts[tid + 256] = 0;
        __syncthreads();
        const int2* e2 = (const int2*)edges;
        int base = p * 8192;
        // phase A: histogram
        for (int c = 0; c < 4; ++c) {
            int ebase = base + c * 2048 + tid * 8;
#pragma unroll
            for (int i = 0; i < 8; ++i) {
                int e = ebase + i;
                if (e < N_EDGES) {
                    int2 ed = e2[e];
                    atomicAdd(&cntd[ed.y >> 8], 1);
                    atomicAdd(&cnts[ed.x >> 8], 1);
                }
            }
        }
        __syncthreads();
        // phase B: block-aggregated reservations (<=512 returning global atomics)
        {
            int c;
            c = cntd[tid];       curd[tid]       = (c > 0) ? atomicAdd(&bucket_next[tid], c) : 0;
            c = cntd[tid + 256]; curd[tid + 256] = (c > 0) ? atomicAdd(&bucket_next[tid + 256], c) : 0;
            c = cnts[tid];       curs[tid]       = (c > 0) ? atomicAdd(&bucket_next[512 + tid], c) : 0;
            c = cnts[tid + 256]; curs[tid + 256] = (c > 0) ? atomicAdd(&bucket_next[512 + tid + 256], c) : 0;
        }
        __syncthreads();
        // phase C: reload (L2-hot) and place
        for (int c = 0; c < 4; ++c) {
            int ebase = base + c * 2048 + tid * 8;
#pragma unroll
            for (int i = 0; i < 8; ++i) {
                int e = ebase + i;
                if (e < N_EDGES) {
                    int2 ed = e2[e];
                    int bd = ed.y >> 8;
                    int sd = atomicAdd(&curd[bd], 1);
                    if (sd < (bd + 1) * CAP_D)
                        bins_dst[sd] = ((ed.y & 255) << 17) | ed.x;
                    int bs = ed.x >> 8;
                    int ss = atomicAdd(&curs[bs], 1);
                    if (ss < (bs + 1) * CAP_D)
                        bins_src[ss] = (unsigned char)(ed.x & 255);
                }
            }
        }
        return;
    }
    // ---------------- gemm1 role: 16 rows/wave, N=128 (8 col-frags), K=192 ----------------
    int g = b - b / 9 - 1;                   // 0..1562
    int lane = tid & 63;
    int wave = tid >> 6;
    int rowbase = g * 64 + wave * 16;
    int lr = lane & 15;
    int lk = (lane >> 4) * 8;

    int row = rowbase + lr;
    int rc = (row < N_NODES) ? row : (N_NODES - 1);
    const float* p = verts + (size_t)rc * IN_DIM + lk;
    short8 a[6];
#pragma unroll
    for (int ks = 0; ks < 6; ++ks) {
        f32x4 u0 = *(const f32x4*)(p + ks * 32);
        f32x4 u1 = *(const f32x4*)(p + ks * 32 + 4);
        short8 t;
        t[0] = f2bf(u0[0]); t[1] = f2bf(u0[1]); t[2] = f2bf(u0[2]); t[3] = f2bf(u0[3]);
        t[4] = f2bf(u1[0]); t[5] = f2bf(u1[1]); t[6] = f2bf(u1[2]); t[7] = f2bf(u1[3]);
        a[ks] = t;
    }

    f32x4 acc[8] = {};
#pragma unroll
    for (int cf = 0; cf < 8; ++cf) {
        const short* bp = Bt1 + (size_t)(cf * 16 + lr) * IN_DIM + lk;
#pragma unroll
        for (int ks = 0; ks < 6; ++ks) {
            short8 bb = *(const short8*)(bp + ks * 32);
            acc[cf] = __builtin_amdgcn_mfma_f32_16x16x32_bf16(a[ks], bb, acc[cf], 0, 0, 0);
        }
    }

    int srow = (lane >> 4) * 4;
#pragma unroll
    for (int cf = 0; cf < 8; ++cf) {
        int colc = cf * 16 + lr;
        float bias = (colc < H1) ? b1[colc] : 0.f;
#pragma unroll
        for (int r = 0; r < 4; ++r) {
            int orow = rowbase + srow + r;
            if (orow < N_NODES) {
                float v = acc[cf][r];
                if (colc < H1) hbase[(size_t)orow * H1 + colc] = f2bf(v + bias);
                else           y1b[(size_t)orow * H1 + (colc - H1)] = f2bf(v);
            }
        }
    }
}

// ---- pass2: per-bucket CSR build + deg histogram -> dinv + y1s = dinv*y1b prescale ----
__global__ __launch_bounds__(256) void csr_kernel(
    const int* __restrict__ bins_dst, const unsigned char* __restrict__ bins_src,
    const int* __restrict__ bucket_next, float* __restrict__ dinv,
    int* __restrict__ row_beg, int* __restrict__ row_end, int* __restrict__ col,
    const unsigned short* __restrict__ y1b, short* __restrict__ y1s) {
    __shared__ int cnt_l[256];
    __shared__ int seg_l[256];
    __shared__ int s[256];
    __shared__ int dcnt[256];
    __shared__ float dinv_l[256];
    int b = blockIdx.x;                  // 0..390
    int tid = threadIdx.x;
    int beg = b * CAP_D;
    int filld = bucket_next[b] - beg;
    if (filld > CAP_D) filld = CAP_D;
    int fills = bucket_next[512 + b] - beg;
    if (fills > CAP_D) fills = CAP_D;
    cnt_l[tid] = 0;
    dcnt[tid] = 0;
    __syncthreads();
    for (int i = tid; i < filld; i += 256)
        atomicAdd(&cnt_l[bins_dst[beg + i] >> 17], 1);
    for (int i = tid; i < fills; i += 256)
        atomicAdd(&dcnt[bins_src[beg + i]], 1);
    __syncthreads();
    int v = cnt_l[tid];
    s[tid] = v;
    __syncthreads();
    for (int off = 1; off < 256; off <<= 1) {
        int t = (tid >= off) ? s[tid - off] : 0;
        __syncthreads();
        s[tid] += t;
        __syncthreads();
    }
    int excl = s[tid] - v;
    seg_l[tid] = beg + excl;             // global cursor for placement
    int n = b * 256 + tid;
    int d = dcnt[tid];
    float dv = (d > 0) ? rsqrtf((float)d) : 0.f;
    dinv_l[tid] = dv;
    if (n < N_NODES) {
        row_beg[n] = beg + excl;
        row_end[n] = beg + excl + v;
        dinv[n] = dv;
    }
    __syncthreads();
    for (int i = tid; i < filld; i += 256) {
        int w = bins_dst[beg + i];
        int slot = atomicAdd(&seg_l[w >> 17], 1);   // LDS returning
        col[slot] = w & 0x1FFFF;
    }
    // y1s = dinv[row] * y1b[row], linear over this block's 256 rows
    int nb = b * 256;
    int nmax = N_NODES - nb; if (nmax > 256) nmax = 256;
    for (int idx = tid; idx < nmax * 8; idx += 256) {
        int r = idx >> 3, j = idx & 7;
        float w = dinv_l[r];
        size_t off = (size_t)(nb + r) * H1 + j * 8;
        short8 vv = *(const short8*)&y1b[off];
        short8 o;
#pragma unroll
        for (int q = 0; q < 8; ++q) o[q] = f2bf(w * bf2f((unsigned short)vv[q]));
        *(short8*)&y1s[off] = o;
    }
}

// ---- fused gather1 + gemm2: 16 nodes/block (6250 blocks, exact) ----
// Phase 1: wave wv gathers nodes nb+wv*4+j (lane=channel), stages relu'd bf16 tile in LDS.
// Phase 2: wave wv computes col-frag wv of the 16x64 tile @ Bt2 via 2 MFMAs;
//          cols 0-31 -> out (+b2), cols 32-63 -> y2s (*dinv[row]).
__global__ __launch_bounds__(256) void g1g2_kernel(
    const int* __restrict__ row_beg, const int* __restrict__ row_end,
    const int* __restrict__ col, const float* __restrict__ dinv,
    const unsigned short* __restrict__ hbase, const unsigned short* __restrict__ y1s,
    const short* __restrict__ Bt2, const float* __restrict__ b2,
    float* __restrict__ out, short* __restrict__ y2s) {
    __shared__ short hb_l[16][68];       // row padded 64->68 to break 128B-stride banks
    int tid = threadIdx.x, lane = tid & 63, wv = tid >> 6;
    int nb = blockIdx.x * 16;
    for (int j = 0; j < 4; ++j) {
        int n = nb + wv * 4 + j;
        int beg = row_beg[n], end = row_end[n];
        float acc = 0.f;
        int i = beg;
        for (; i + 8 <= end; i += 8) {
            int s0 = col[i], s1 = col[i + 1], s2 = col[i + 2], s3 = col[i + 3];
            int s4 = col[i + 4], s5 = col[i + 5], s6 = col[i + 6], s7 = col[i + 7];
            float v0 = bf2f(y1s[(size_t)s0 * H1 + lane]);
            float v1 = bf2f(y1s[(size_t)s1 * H1 + lane]);
            float v2 = bf2f(y1s[(size_t)s2 * H1 + lane]);
            float v3 = bf2f(y1s[(size_t)s3 * H1 + lane]);
            float v4 = bf2f(y1s[(size_t)s4 * H1 + lane]);
            float v5 = bf2f(y1s[(size_t)s5 * H1 + lane]);
            float v6 = bf2f(y1s[(size_t)s6 * H1 + lane]);
            float v7 = bf2f(y1s[(size_t)s7 * H1 + lane]);
            acc += ((v0 + v1) + (v2 + v3)) + ((v4 + v5) + (v6 + v7));
        }
        for (; i + 4 <= end; i += 4) {
            int s0 = col[i], s1 = col[i + 1], s2 = col[i + 2], s3 = col[i + 3];
            float v0 = bf2f(y1s[(size_t)s0 * H1 + lane]);
            float v1 = bf2f(y1s[(size_t)s1 * H1 + lane]);
            float v2 = bf2f(y1s[(size_t)s2 * H1 + lane]);
            float v3 = bf2f(y1s[(size_t)s3 * H1 + lane]);
            acc += (v0 + v1) + (v2 + v3);
        }
        for (; i < end; ++i)
            acc += bf2f(y1s[(size_t)col[i] * H1 + lane]);
        float hf = bf2f(hbase[(size_t)n * H1 + lane]) - dinv[n] * acc;
        hb_l[wv * 4 + j][lane] = f2bf(fmaxf(hf, 0.f));
    }
    __syncthreads();
    // gemm phase
    int lr = lane & 15;
    int lk = (lane >> 4) * 8;
    short8 a0 = *(const short8*)&hb_l[lr][lk];
    short8 a1 = *(const short8*)&hb_l[lr][32 + lk];
    const short* bp = Bt2 + (size_t)(wv * 16 + lr) * H1 + lk;
    short8 b0 = *(const short8*)(bp);
    short8 b1 = *(const short8*)(bp + 32);
    f32x4 acc2 = {};
    acc2 = __builtin_amdgcn_mfma_f32_16x16x32_bf16(a0, b0, acc2, 0, 0, 0);
    acc2 = __builtin_amdgcn_mfma_f32_16x16x32_bf16(a1, b1, acc2, 0, 0, 0);
    int srow = (lane >> 4) * 4;
    int colc = wv * 16 + lr;
    float bias = (colc < H2) ? b2[colc] : 0.f;
#pragma unroll
    for (int r = 0; r < 4; ++r) {
        int n = nb + srow + r;
        float v = acc2[r];
        if (colc < H2) out[(size_t)n * H2 + colc] = v + bias;
        else           y2s[(size_t)n * H2 + (colc - H2)] = f2bf(dinv[n] * v);
    }
}

// ------- gather layer 2: out[n] -= dinv[n] * sum(y2s[src]); 2 nodes/wave, 8/4/1 unroll -------
__global__ __launch_bounds__(256) void gather2_kernel(
    const int* __restrict__ row_beg, const int* __restrict__ row_end,
    const int* __restrict__ col, const float* __restrict__ dinv,
    const unsigned short* __restrict__ y2s, float* __restrict__ out) {
    int wave = (blockIdx.x * 256 + threadIdx.x) >> 6;
    int lane = threadIdx.x & 63;
    int n = wave * 2 + (lane >> 5);
    if (n >= N_NODES) return;
    int c32 = lane & 31;
    int beg = row_beg[n], end = row_end[n];
    float acc = 0.f;
    int i = beg;
    for (; i + 8 <= end; i += 8) {
        int s0 = col[i], s1 = col[i + 1], s2 = col[i + 2], s3 = col[i + 3];
        int s4 = col[i + 4], s5 = col[i + 5], s6 = col[i + 6], s7 = col[i + 7];
        float v0 = bf2f(y2s[(size_t)s0 * H2 + c32]);
        float v1 = bf2f(y2s[(size_t)s1 * H2 + c32]);
        float v2 = bf2f(y2s[(size_t)s2 * H2 + c32]);
        float v3 = bf2f(y2s[(size_t)s3 * H2 + c32]);
        float v4 = bf2f(y2s[(size_t)s4 * H2 + c32]);
        float v5 = bf2f(y2s[(size_t)s5 * H2 + c32]);
        float v6 = bf2f(y2s[(size_t)s6 * H2 + c32]);
        float v7 = bf2f(y2s[(size_t)s7 * H2 + c32]);
        acc += ((v0 + v1) + (v2 + v3)) + ((v4 + v5) + (v6 + v7));
    }
    for (; i + 4 <= end; i += 4) {
        int s0 = col[i], s1 = col[i + 1], s2 = col[i + 2], s3 = col[i + 3];
        float v0 = bf2f(y2s[(size_t)s0 * H2 + c32]);
        float v1 = bf2f(y2s[(size_t)s1 * H2 + c32]);
        float v2 = bf2f(y2s[(size_t)s2 * H2 + c32]);
        float v3 = bf2f(y2s[(size_t)s3 * H2 + c32]);
        acc += (v0 + v1) + (v2 + v3);
    }
    for (; i < end; ++i)
        acc += bf2f(y2s[(size_t)col[i] * H2 + c32]);
    size_t idx = (size_t)n * H2 + c32;
    out[idx] = out[idx] - dinv[n] * acc;
}

extern "C" void kernel_launch(void* const* d_in, const int* in_sizes, int n_in,
                              void* d_out, int out_size, void* d_ws, size_t ws_size,
                              hipStream_t stream) {
    const float* verts = (const float*)d_in[0];
    const int*   edges = (const int*)  d_in[1];
    const float* W0_1  = (const float*)d_in[2];
    const float* W1_1  = (const float*)d_in[3];
    const float* b1    = (const float*)d_in[4];
    const float* W0_2  = (const float*)d_in[5];
    const float* W1_2  = (const float*)d_in[6];
    const float* b2    = (const float*)d_in[7];
    float* out = (float*)d_out;

    char* ws = (char*)d_ws;
    auto align256 = [](size_t x) { return (x + 255) & ~(size_t)255; };
    size_t o = 0;
    auto alloc = [&](size_t bytes) { size_t r = o; o = align256(o + bytes); return r; };

    int*   bucket_next = (int*)  (ws + alloc((size_t)1024 * 4));
    int*   bins_dst    = (int*)  (ws + alloc((size_t)NBKT * CAP_D * 4));
    unsigned char* bins_src = (unsigned char*)(ws + alloc((size_t)NBKT * CAP_D));
    int*   col         = (int*)  (ws + alloc((size_t)NBKT * CAP_D * 4));
    int*   row_beg     = (int*)  (ws + alloc((size_t)N_NODES * 4));
    int*   row_end     = (int*)  (ws + alloc((size_t)N_NODES * 4));
    float* dinv        = (float*)(ws + alloc((size_t)N_NODES * 4));
    short* Bt1         = (short*)(ws + alloc((size_t)128 * IN_DIM * 2));
    short* Bt2         = (short*)(ws + alloc((size_t)64 * H1 * 2));
    short* hbase       = (short*)(ws + alloc((size_t)N_NODES * H1 * 2));
    short* y1b         = (short*)(ws + alloc((size_t)N_NODES * H1 * 2));
    short* y1s         = (short*)(ws + alloc((size_t)N_NODES * H1 * 2));
    short* y2s         = (short*)(ws + alloc((size_t)N_NODES * H2 * 2));

    prep_w_kernel<<<112, 256, 0, stream>>>(W0_1, W1_1, W0_2, W1_2, Bt1, Bt2, bucket_next);

    k1_fused  <<<K1GRID, 256, 0, stream>>>(edges, bucket_next, bins_dst, bins_src,
                                           verts, Bt1, b1, hbase, y1b);
    csr_kernel<<<NBKT, 256, 0, stream>>>(bins_dst, bins_src, bucket_next, dinv,
                                         row_beg, row_end, col,
                                         (const unsigned short*)y1b, y1s);

    g1g2_kernel<<<N_NODES / 16, 256, 0, stream>>>(row_beg, row_end, col, dinv,
                                                  (const unsigned short*)hbase,
                                                  (const unsigned short*)y1s,
                                                  Bt2, b2, out, y2s);
    gather2_kernel<<<(N_NODES + 7) / 8, 256, 0, stream>>>(row_beg, row_end, col, dinv,
                                                          (const unsigned short*)y2s, out);
}

// Round 12
// 197.594 us; speedup vs baseline: 1.0644x; 1.0644x over previous
//
#include <hip/hip_runtime.h>

#define N_NODES 100000
#define N_EDGES 1600000
#define IN_DIM  192
#define H1      64
#define H2      32
#define NBKT    391          // ceil(N_NODES/256) buckets (both dst- and src-keyed)
#define CAP_D   4608         // bucket capacity (mean 4096, sigma 64 -> 8 sigma)
#define K1GRID  2345         // b%3==0 -> pass1 (782), else gemm1 (1563)

typedef __attribute__((ext_vector_type(8))) short short8;
typedef __attribute__((ext_vector_type(4))) float f32x4;

__device__ inline short f2bf(float f) {
    union { float f; unsigned u; } v; v.f = f;
    unsigned r = (v.u + 0x7FFFu + ((v.u >> 16) & 1u)) >> 16;
    return (short)r;
}
__device__ inline float bf2f(unsigned short s) {
    union { unsigned u; float f; } v; v.u = ((unsigned)s) << 16;
    return v.f;
}

// ------- weight prep: Bt1[128][192], Bt2[64][64], bf16, N-major; block 0 inits cursors -------
__global__ __launch_bounds__(256) void prep_w_kernel(
    const float* __restrict__ W0_1, const float* __restrict__ W1_1,
    const float* __restrict__ W0_2, const float* __restrict__ W1_2,
    short* __restrict__ Bt1, short* __restrict__ Bt2, int* __restrict__ bucket_next) {
    if (blockIdx.x == 0) {
        for (int i = threadIdx.x; i < 1024; i += 256)
            bucket_next[i] = (i & 511) * CAP_D;
    }
    int idx = blockIdx.x * 256 + threadIdx.x;
    if (idx < 128 * IN_DIM) {
        int n = idx / IN_DIM, k = idx % IN_DIM;
        float v = (n < H1) ? W0_1[(size_t)k * H1 + n] : W1_1[(size_t)k * H1 + (n - H1)];
        Bt1[idx] = f2bf(v);
    } else {
        int j = idx - 128 * IN_DIM;
        if (j < 64 * H1) {
            int n = j / H1, k = j % H1;
            float v = (n < H2) ? W0_2[(size_t)k * H2 + n] : W1_2[(size_t)k * H2 + (n - H2)];
            Bt2[j] = f2bf(v);
        }
    }
}

// ---- K1 fused: pass1 dual binning (2048 edges/block, regs held) || gemm1 MFMA ----
__global__ __launch_bounds__(256) void k1_fused(
    const int* __restrict__ edges, int* __restrict__ bucket_next,
    int* __restrict__ bins_dst, unsigned char* __restrict__ bins_src,
    const float* __restrict__ verts, const short* __restrict__ Bt1,
    const float* __restrict__ b1, short* __restrict__ hbase, short* __restrict__ y1b) {
    __shared__ int cntd[512];
    __shared__ int curd[512];
    __shared__ int cnts[512];
    __shared__ int curs[512];
    int b = blockIdx.x;
    int tid = threadIdx.x;
    if (b % 3 == 0) {
        // ---------------- pass1 role: 2048 edges, payload kept in registers ----------------
        int p = b / 3;                       // 0..781
        cntd[tid] = 0; cntd[tid + 256] = 0;
        cnts[tid] = 0; cnts[tid + 256] = 0;
        __syncthreads();
        int ebase = p * 2048 + tid * 8;
        int2 ed[8]; int bd[8], bs[8];
#pragma unroll
        for (int i = 0; i < 8; ++i) {
            int e = ebase + i;
            if (e < N_EDGES) {
                ed[i] = ((const int2*)edges)[e];
                bd[i] = ed[i].y >> 8;
                bs[i] = ed[i].x >> 8;
                atomicAdd(&cntd[bd[i]], 1);
                atomicAdd(&cnts[bs[i]], 1);
            } else { bd[i] = -1; bs[i] = -1; }
        }
        __syncthreads();
        {
            int c;
            c = cntd[tid];       curd[tid]       = (c > 0) ? atomicAdd(&bucket_next[tid], c) : 0;
            c = cntd[tid + 256]; curd[tid + 256] = (c > 0) ? atomicAdd(&bucket_next[tid + 256], c) : 0;
            c = cnts[tid];       curs[tid]       = (c > 0) ? atomicAdd(&bucket_next[512 + tid], c) : 0;
            c = cnts[tid + 256]; curs[tid + 256] = (c > 0) ? atomicAdd(&bucket_next[512 + tid + 256], c) : 0;
        }
        __syncthreads();
#pragma unroll
        for (int i = 0; i < 8; ++i) {
            if (bd[i] >= 0) {
                int sd = atomicAdd(&curd[bd[i]], 1);
                if (sd < (bd[i] + 1) * CAP_D)
                    bins_dst[sd] = ((ed[i].y & 255) << 17) | ed[i].x;
                int ss = atomicAdd(&curs[bs[i]], 1);
                if (ss < (bs[i] + 1) * CAP_D)
                    bins_src[ss] = (unsigned char)(ed[i].x & 255);
            }
        }
        return;
    }
    // ---------------- gemm1 role: 16 rows/wave, N=128 (8 col-frags), K=192 ----------------
    int g = b - b / 3 - 1;                   // 0..1562
    int lane = tid & 63;
    int wave = tid >> 6;
    int rowbase = g * 64 + wave * 16;
    int lr = lane & 15;
    int lk = (lane >> 4) * 8;

    int row = rowbase + lr;
    int rc = (row < N_NODES) ? row : (N_NODES - 1);
    const float* p = verts + (size_t)rc * IN_DIM + lk;
    short8 a[6];
#pragma unroll
    for (int ks = 0; ks < 6; ++ks) {
        f32x4 u0 = *(const f32x4*)(p + ks * 32);
        f32x4 u1 = *(const f32x4*)(p + ks * 32 + 4);
        short8 t;
        t[0] = f2bf(u0[0]); t[1] = f2bf(u0[1]); t[2] = f2bf(u0[2]); t[3] = f2bf(u0[3]);
        t[4] = f2bf(u1[0]); t[5] = f2bf(u1[1]); t[6] = f2bf(u1[2]); t[7] = f2bf(u1[3]);
        a[ks] = t;
    }

    f32x4 acc[8] = {};
#pragma unroll
    for (int cf = 0; cf < 8; ++cf) {
        const short* bp = Bt1 + (size_t)(cf * 16 + lr) * IN_DIM + lk;
#pragma unroll
        for (int ks = 0; ks < 6; ++ks) {
            short8 bb = *(const short8*)(bp + ks * 32);
            acc[cf] = __builtin_amdgcn_mfma_f32_16x16x32_bf16(a[ks], bb, acc[cf], 0, 0, 0);
        }
    }

    int srow = (lane >> 4) * 4;
#pragma unroll
    for (int cf = 0; cf < 8; ++cf) {
        int colc = cf * 16 + lr;
        float bias = (colc < H1) ? b1[colc] : 0.f;
#pragma unroll
        for (int r = 0; r < 4; ++r) {
            int orow = rowbase + srow + r;
            if (orow < N_NODES) {
                float v = acc[cf][r];
                if (colc < H1) hbase[(size_t)orow * H1 + colc] = f2bf(v + bias);
                else           y1b[(size_t)orow * H1 + (colc - H1)] = f2bf(v);
            }
        }
    }
}

// ---- pass2: per-bucket CSR build + deg histogram -> dinv + y1s = dinv*y1b prescale ----
__global__ __launch_bounds__(256) void csr_kernel(
    const int* __restrict__ bins_dst, const unsigned char* __restrict__ bins_src,
    const int* __restrict__ bucket_next, float* __restrict__ dinv,
    int* __restrict__ row_beg, int* __restrict__ row_end, int* __restrict__ col,
    const unsigned short* __restrict__ y1b, short* __restrict__ y1s) {
    __shared__ int cnt_l[256];
    __shared__ int seg_l[256];
    __shared__ int s[256];
    __shared__ int dcnt[256];
    __shared__ float dinv_l[256];
    int b = blockIdx.x;                  // 0..390
    int tid = threadIdx.x;
    int beg = b * CAP_D;
    int filld = bucket_next[b] - beg;
    if (filld > CAP_D) filld = CAP_D;
    int fills = bucket_next[512 + b] - beg;
    if (fills > CAP_D) fills = CAP_D;
    cnt_l[tid] = 0;
    dcnt[tid] = 0;
    __syncthreads();
    for (int i = tid; i < filld; i += 256)
        atomicAdd(&cnt_l[bins_dst[beg + i] >> 17], 1);
    for (int i = tid; i < fills; i += 256)
        atomicAdd(&dcnt[bins_src[beg + i]], 1);
    __syncthreads();
    int v = cnt_l[tid];
    s[tid] = v;
    __syncthreads();
    for (int off = 1; off < 256; off <<= 1) {
        int t = (tid >= off) ? s[tid - off] : 0;
        __syncthreads();
        s[tid] += t;
        __syncthreads();
    }
    int excl = s[tid] - v;
    seg_l[tid] = beg + excl;             // global cursor for placement
    int n = b * 256 + tid;
    int d = dcnt[tid];
    float dv = (d > 0) ? rsqrtf((float)d) : 0.f;
    dinv_l[tid] = dv;
    if (n < N_NODES) {
        row_beg[n] = beg + excl;
        row_end[n] = beg + excl + v;
        dinv[n] = dv;
    }
    __syncthreads();
    for (int i = tid; i < filld; i += 256) {
        int w = bins_dst[beg + i];
        int slot = atomicAdd(&seg_l[w >> 17], 1);   // LDS returning
        col[slot] = w & 0x1FFFF;
    }
    // y1s = dinv[row] * y1b[row], linear over this block's 256 rows
    int nb = b * 256;
    int nmax = N_NODES - nb; if (nmax > 256) nmax = 256;
    for (int idx = tid; idx < nmax * 8; idx += 256) {
        int r = idx >> 3, j = idx & 7;
        float w = dinv_l[r];
        size_t off = (size_t)(nb + r) * H1 + j * 8;
        short8 vv = *(const short8*)&y1b[off];
        short8 o;
#pragma unroll
        for (int q = 0; q < 8; ++q) o[q] = f2bf(w * bf2f((unsigned short)vv[q]));
        *(short8*)&y1s[off] = o;
    }
}

// ---- fused gather1 + gemm2: 16 nodes/block (6250 blocks, exact) ----
__global__ __launch_bounds__(256) void g1g2_kernel(
    const int* __restrict__ row_beg, const int* __restrict__ row_end,
    const int* __restrict__ col, const float* __restrict__ dinv,
    const unsigned short* __restrict__ hbase, const unsigned short* __restrict__ y1s,
    const short* __restrict__ Bt2, const float* __restrict__ b2,
    float* __restrict__ out, short* __restrict__ y2s) {
    __shared__ short hb_l[16][68];       // row padded 64->68 to break 128B-stride banks
    int tid = threadIdx.x, lane = tid & 63, wv = tid >> 6;
    int nb = blockIdx.x * 16;
    for (int j = 0; j < 4; ++j) {
        int n = nb + wv * 4 + j;
        int beg = row_beg[n], end = row_end[n];
        float acc = 0.f;
        int i = beg;
        for (; i + 8 <= end; i += 8) {
            int s0 = col[i], s1 = col[i + 1], s2 = col[i + 2], s3 = col[i + 3];
            int s4 = col[i + 4], s5 = col[i + 5], s6 = col[i + 6], s7 = col[i + 7];
            float v0 = bf2f(y1s[(size_t)s0 * H1 + lane]);
            float v1 = bf2f(y1s[(size_t)s1 * H1 + lane]);
            float v2 = bf2f(y1s[(size_t)s2 * H1 + lane]);
            float v3 = bf2f(y1s[(size_t)s3 * H1 + lane]);
            float v4 = bf2f(y1s[(size_t)s4 * H1 + lane]);
            float v5 = bf2f(y1s[(size_t)s5 * H1 + lane]);
            float v6 = bf2f(y1s[(size_t)s6 * H1 + lane]);
            float v7 = bf2f(y1s[(size_t)s7 * H1 + lane]);
            acc += ((v0 + v1) + (v2 + v3)) + ((v4 + v5) + (v6 + v7));
        }
        for (; i + 4 <= end; i += 4) {
            int s0 = col[i], s1 = col[i + 1], s2 = col[i + 2], s3 = col[i + 3];
            float v0 = bf2f(y1s[(size_t)s0 * H1 + lane]);
            float v1 = bf2f(y1s[(size_t)s1 * H1 + lane]);
            float v2 = bf2f(y1s[(size_t)s2 * H1 + lane]);
            float v3 = bf2f(y1s[(size_t)s3 * H1 + lane]);
            acc += (v0 + v1) + (v2 + v3);
        }
        for (; i < end; ++i)
            acc += bf2f(y1s[(size_t)col[i] * H1 + lane]);
        float hf = bf2f(hbase[(size_t)n * H1 + lane]) - dinv[n] * acc;
        hb_l[wv * 4 + j][lane] = f2bf(fmaxf(hf, 0.f));
    }
    __syncthreads();
    // gemm phase
    int lr = lane & 15;
    int lk = (lane >> 4) * 8;
    short8 a0 = *(const short8*)&hb_l[lr][lk];
    short8 a1 = *(const short8*)&hb_l[lr][32 + lk];
    const short* bp = Bt2 + (size_t)(wv * 16 + lr) * H1 + lk;
    short8 b0 = *(const short8*)(bp);
    short8 b1 = *(const short8*)(bp + 32);
    f32x4 acc2 = {};
    acc2 = __builtin_amdgcn_mfma_f32_16x16x32_bf16(a0, b0, acc2, 0, 0, 0);
    acc2 = __builtin_amdgcn_mfma_f32_16x16x32_bf16(a1, b1, acc2, 0, 0, 0);
    int srow = (lane >> 4) * 4;
    int colc = wv * 16 + lr;
    float bias = (colc < H2) ? b2[colc] : 0.f;
#pragma unroll
    for (int r = 0; r < 4; ++r) {
        int n = nb + srow + r;
        float v = acc2[r];
        if (colc < H2) out[(size_t)n * H2 + colc] = v + bias;
        else           y2s[(size_t)n * H2 + (colc - H2)] = f2bf(dinv[n] * v);
    }
}

// ------- gather layer 2: out[n] -= dinv[n] * sum(y2s[src]); 2 nodes/wave, 8/4/1 unroll -------
__global__ __launch_bounds__(256) void gather2_kernel(
    const int* __restrict__ row_beg, const int* __restrict__ row_end,
    const int* __restrict__ col, const float* __restrict__ dinv,
    const unsigned short* __restrict__ y2s, float* __restrict__ out) {
    int wave = (blockIdx.x * 256 + threadIdx.x) >> 6;
    int lane = threadIdx.x & 63;
    int n = wave * 2 + (lane >> 5);
    if (n >= N_NODES) return;
    int c32 = lane & 31;
    int beg = row_beg[n], end = row_end[n];
    float acc = 0.f;
    int i = beg;
    for (; i + 8 <= end; i += 8) {
        int s0 = col[i], s1 = col[i + 1], s2 = col[i + 2], s3 = col[i + 3];
        int s4 = col[i + 4], s5 = col[i + 5], s6 = col[i + 6], s7 = col[i + 7];
        float v0 = bf2f(y2s[(size_t)s0 * H2 + c32]);
        float v1 = bf2f(y2s[(size_t)s1 * H2 + c32]);
        float v2 = bf2f(y2s[(size_t)s2 * H2 + c32]);
        float v3 = bf2f(y2s[(size_t)s3 * H2 + c32]);
        float v4 = bf2f(y2s[(size_t)s4 * H2 + c32]);
        float v5 = bf2f(y2s[(size_t)s5 * H2 + c32]);
        float v6 = bf2f(y2s[(size_t)s6 * H2 + c32]);
        float v7 = bf2f(y2s[(size_t)s7 * H2 + c32]);
        acc += ((v0 + v1) + (v2 + v3)) + ((v4 + v5) + (v6 + v7));
    }
    for (; i + 4 <= end; i += 4) {
        int s0 = col[i], s1 = col[i + 1], s2 = col[i + 2], s3 = col[i + 3];
        float v0 = bf2f(y2s[(size_t)s0 * H2 + c32]);
        float v1 = bf2f(y2s[(size_t)s1 * H2 + c32]);
        float v2 = bf2f(y2s[(size_t)s2 * H2 + c32]);
        float v3 = bf2f(y2s[(size_t)s3 * H2 + c32]);
        acc += (v0 + v1) + (v2 + v3);
    }
    for (; i < end; ++i)
        acc += bf2f(y2s[(size_t)col[i] * H2 + c32]);
    size_t idx = (size_t)n * H2 + c32;
    out[idx] = out[idx] - dinv[n] * acc;
}

extern "C" void kernel_launch(void* const* d_in, const int* in_sizes, int n_in,
                              void* d_out, int out_size, void* d_ws, size_t ws_size,
                              hipStream_t stream) {
    const float* verts = (const float*)d_in[0];
    const int*   edges = (const int*)  d_in[1];
    const float* W0_1  = (const float*)d_in[2];
    const float* W1_1  = (const float*)d_in[3];
    const float* b1    = (const float*)d_in[4];
    const float* W0_2  = (const float*)d_in[5];
    const float* W1_2  = (const float*)d_in[6];
    const float* b2    = (const float*)d_in[7];
    float* out = (float*)d_out;

    char* ws = (char*)d_ws;
    auto align256 = [](size_t x) { return (x + 255) & ~(size_t)255; };
    size_t o = 0;
    auto alloc = [&](size_t bytes) { size_t r = o; o = align256(o + bytes); return r; };

    int*   bucket_next = (int*)  (ws + alloc((size_t)1024 * 4));
    int*   bins_dst    = (int*)  (ws + alloc((size_t)NBKT * CAP_D * 4));
    unsigned char* bins_src = (unsigned char*)(ws + alloc((size_t)NBKT * CAP_D));
    int*   col         = (int*)  (ws + alloc((size_t)NBKT * CAP_D * 4));
    int*   row_beg     = (int*)  (ws + alloc((size_t)N_NODES * 4));
    int*   row_end     = (int*)  (ws + alloc((size_t)N_NODES * 4));
    float* dinv        = (float*)(ws + alloc((size_t)N_NODES * 4));
    short* Bt1         = (short*)(ws + alloc((size_t)128 * IN_DIM * 2));
    short* Bt2         = (short*)(ws + alloc((size_t)64 * H1 * 2));
    short* hbase       = (short*)(ws + alloc((size_t)N_NODES * H1 * 2));
    short* y1b         = (short*)(ws + alloc((size_t)N_NODES * H1 * 2));
    short* y1s         = (short*)(ws + alloc((size_t)N_NODES * H1 * 2));
    short* y2s         = (short*)(ws + alloc((size_t)N_NODES * H2 * 2));

    prep_w_kernel<<<112, 256, 0, stream>>>(W0_1, W1_1, W0_2, W1_2, Bt1, Bt2, bucket_next);

    k1_fused  <<<K1GRID, 256, 0, stream>>>(edges, bucket_next, bins_dst, bins_src,
                                           verts, Bt1, b1, hbase, y1b);
    csr_kernel<<<NBKT, 256, 0, stream>>>(bins_dst, bins_src, bucket_next, dinv,
                                         row_beg, row_end, col,
                                         (const unsigned short*)y1b, y1s);

    g1g2_kernel<<<N_NODES / 16, 256, 0, stream>>>(row_beg, row_end, col, dinv,
                                                  (const unsigned short*)hbase,
                                                  (const unsigned short*)y1s,
                                                  Bt2, b2, out, y2s);
    gather2_kernel<<<(N_NODES + 7) / 8, 256, 0, stream>>>(row_beg, row_end, col, dinv,
                                                          (const unsigned short*)y2s, out);
}